// Round 2
// baseline (645508.643 us; speedup 1.0000x reference)
//
#include <hip/hip_runtime.h>
#include <cstddef>

// ---------------- problem constants ----------------
// B=32, T_IN=512, T_OUT=800, N_MEL=80, ENC=512, ARNN=DRNN=1024, PRE=256,
// ATT=128, LOCF=32, LOCK=31.  4*ARNN = 4096 gate rows.

// ---------------- workspace layout (float offsets) ----------------
constexpr size_t WT_ATT = 0;                            // [1792][4096]
constexpr size_t WT_DEC = WT_ATT + 1792ull * 4096;      // [2560][4096]
constexpr size_t PREN_O = WT_DEC + 2560ull * 4096;      // [800][32][256]
constexpr size_t PMEMT  = PREN_O + 800ull * 32 * 256;   // [32][128][512]
constexpr size_t W1T    = PMEMT + 32ull * 128 * 512;    // [80][256]
constexpr size_t W2T    = W1T + 80 * 256;               // [256][256]
constexpr size_t QWT    = W2T + 256 * 256;              // [1024][128]
constexpr size_t PWT    = QWT + 1024 * 128;             // [1536][96] (cols 0..79 mel, 80 gate)
constexpr size_t MEMWT  = PWT + 1536 * 96;              // [512][128]
constexpr size_t XATT   = MEMWT + 512 * 128;            // [2][32][1792]  (pren|actx|ah)
constexpr size_t XDEC   = XATT + 2ull * 32 * 1792;      // [32][2560]     (ah|dh|actx)
constexpr size_t AH_O   = XDEC + 32ull * 2560;          // [32][1024]
constexpr size_t AC_O   = AH_O + 32 * 1024;
constexpr size_t DH_O   = AC_O + 32 * 1024;
constexpr size_t DC_O   = DH_O + 32 * 1024;
constexpr size_t AW_O   = DC_O + 32 * 1024;             // [32][512]
constexpr size_t AWC_O  = AW_O + 32 * 512;              // [32][512]
constexpr size_t ACTX_O = AWC_O + 32 * 512;             // [2][32][512]
constexpr size_t ENER_O = ACTX_O + 2ull * 32 * 512;     // [32][512]
constexpr size_t ZATT_O = ENER_O + 32 * 512;            // [3][32][4096]
constexpr size_t ZDEC_O = ZATT_O + 3ull * 32 * 4096;    // [4][32][4096]

constexpr size_t MEL_OUT = 0;                 // [32][80][800]
constexpr size_t GATE_OUT = 2048000;          // [32][800]
constexpr size_t ALIGN_OUT = 2073600;         // [32][800][512]

// ---------------- software grid barrier ----------------
// Zero-initialized at module load; counter self-resets every barrier and the
// generation only grows, so state is valid across repeated graph replays.
__device__ unsigned g_bar_count = 0;
__device__ unsigned g_bar_gen = 0;

__device__ __forceinline__ void gsync() {
  __syncthreads();
  if (threadIdx.x == 0) {
    const unsigned g =
        __hip_atomic_load(&g_bar_gen, __ATOMIC_RELAXED, __HIP_MEMORY_SCOPE_AGENT);
    __threadfence();  // make this block's writes visible device-wide
    const unsigned pos = __hip_atomic_fetch_add(&g_bar_count, 1u, __ATOMIC_ACQ_REL,
                                                __HIP_MEMORY_SCOPE_AGENT);
    if (pos == gridDim.x - 1) {
      __hip_atomic_store(&g_bar_count, 0u, __ATOMIC_RELAXED,
                         __HIP_MEMORY_SCOPE_AGENT);
      __hip_atomic_fetch_add(&g_bar_gen, 1u, __ATOMIC_RELEASE,
                             __HIP_MEMORY_SCOPE_AGENT);
    } else {
      while (__hip_atomic_load(&g_bar_gen, __ATOMIC_ACQUIRE,
                               __HIP_MEMORY_SCOPE_AGENT) == g) {
        __builtin_amdgcn_s_sleep(1);
      }
    }
    __threadfence();  // invalidate caches before reading others' writes
  }
  __syncthreads();
}

// ---------------- helpers ----------------
__device__ __forceinline__ float sigf(float x) {
  float cx = fminf(fmaxf(x, -30.f), 30.f);
  return 1.f / (1.f + __expf(-cx));
}
__device__ __forceinline__ float tanh_f(float x) {
  float cx = fminf(fmaxf(x, -15.f), 15.f);
  float e = __expf(2.f * cx);
  return (e - 1.f) / (e + 1.f);
}

// Z_partial[b][4096] for rows gb*64..gb*64+63, K range [klo,khi).
// X: [32][xstride], WT: [K][4096] transposed weights.
__device__ __forceinline__ void gemm_partial(
    const float* __restrict__ X, int xstride, const float* __restrict__ WT,
    int klo, int khi, float* __restrict__ zp, int gb, int tid, float* xs) {
  const int b = tid & 31, gt = tid >> 5;
  const int g0 = gb * 64 + gt * 8;
  float acc0 = 0, acc1 = 0, acc2 = 0, acc3 = 0, acc4 = 0, acc5 = 0, acc6 = 0, acc7 = 0;
  for (int kc = klo; kc < khi; kc += 256) {
    const int cn = (khi - kc < 256) ? (khi - kc) : 256;
    const int cn4 = cn >> 2;
    __syncthreads();
    for (int i = tid; i < 32 * cn4; i += 256) {
      const int r = i / cn4, c = i - r * cn4;
      *(float4*)(xs + r * 260 + c * 4) =
          *(const float4*)(X + (size_t)r * xstride + kc + c * 4);
    }
    __syncthreads();
    const float* wb = WT + (size_t)kc * 4096 + g0;
    for (int kk = 0; kk < cn; kk += 4) {
      const float4 xv = *(const float4*)(xs + b * 260 + kk);
      const float* w0p = wb + (size_t)kk * 4096;
#define GSTEP(J, XJ)                                                     \
  {                                                                      \
    const float4 wA = *(const float4*)(w0p + (size_t)(J) * 4096);        \
    const float4 wB = *(const float4*)(w0p + (size_t)(J) * 4096 + 4);    \
    acc0 = fmaf(XJ, wA.x, acc0); acc1 = fmaf(XJ, wA.y, acc1);            \
    acc2 = fmaf(XJ, wA.z, acc2); acc3 = fmaf(XJ, wA.w, acc3);            \
    acc4 = fmaf(XJ, wB.x, acc4); acc5 = fmaf(XJ, wB.y, acc5);            \
    acc6 = fmaf(XJ, wB.z, acc6); acc7 = fmaf(XJ, wB.w, acc7);            \
  }
      GSTEP(0, xv.x) GSTEP(1, xv.y) GSTEP(2, xv.z) GSTEP(3, xv.w)
#undef GSTEP
    }
  }
  float* zr = zp + (size_t)b * 4096 + g0;
  *(float4*)zr = make_float4(acc0, acc1, acc2, acc3);
  *(float4*)(zr + 4) = make_float4(acc4, acc5, acc6, acc7);
}

// ---------------- setup kernels ----------------
__global__ __launch_bounds__(256) void k_small(
    const float* __restrict__ w1, const float* __restrict__ w2,
    const float* __restrict__ qw, const float* __restrict__ memw,
    const float* __restrict__ projw, const float* __restrict__ gatew,
    float* __restrict__ ws) {
  size_t i = (size_t)blockIdx.x * 256 + threadIdx.x;
  if (i < 20480) { size_t j = i & 255, m = i >> 8; ws[W1T + m * 256 + j] = w1[j * 80 + m]; return; }
  i -= 20480;
  if (i < 65536) { size_t j = i & 255, k = i >> 8; ws[W2T + k * 256 + j] = w2[j * 256 + k]; return; }
  i -= 65536;
  if (i < 131072) { size_t j = i & 127, k = i >> 7; ws[QWT + k * 128 + j] = qw[j * 1024 + k]; return; }
  i -= 131072;
  if (i < 65536) { size_t a = i & 127, e = i >> 7; ws[MEMWT + e * 128 + a] = memw[a * 512 + e]; return; }
  i -= 65536;
  if (i < 147456) {
    size_t o = i % 96, k = i / 96;
    float v = 0.f;
    if (o < 80) v = projw[o * 1536 + k];
    else if (o == 80) v = gatew[k];
    ws[PWT + k * 96 + o] = v;
  }
}

__global__ __launch_bounds__(256) void k_wt_att(const float* __restrict__ wih,
                                                const float* __restrict__ whh,
                                                float* __restrict__ ws) {
  const size_t i = (size_t)blockIdx.x * 256 + threadIdx.x;  // = k*4096 + g
  const size_t g = i & 4095, k = i >> 12;
  ws[WT_ATT + i] = (k < 768) ? wih[g * 768 + k] : whh[g * 1024 + (k - 768)];
}

__global__ __launch_bounds__(256) void k_wt_dec(const float* __restrict__ wih,
                                                const float* __restrict__ whh,
                                                float* __restrict__ ws) {
  const size_t i = (size_t)blockIdx.x * 256 + threadIdx.x;
  const size_t g = i & 4095, k = i >> 12;
  float v;
  if (k < 1024) v = wih[g * 1536 + k];                       // ah part of wih
  else if (k < 2048) v = whh[g * 1024 + (k - 1024)];         // dh (whh)
  else v = wih[g * 1536 + 1024 + (k - 2048)];                // actx part of wih
  ws[WT_DEC + i] = v;
}

__global__ __launch_bounds__(256) void k_xdec0(float* __restrict__ ws) {
  const int i = blockIdx.x * 256 + threadIdx.x;  // < 32768
  const int b = i >> 10, j = i & 1023;
  ws[XDEC + (size_t)b * 2560 + 1024 + j] = 0.f;
}

__global__ __launch_bounds__(256) void k_prenet(const float* __restrict__ din,
                                                float* __restrict__ ws) {
  __shared__ float h1[8][257];
  const int tg = blockIdx.x, b = blockIdx.y, j = threadIdx.x;
  float acc[8] = {0, 0, 0, 0, 0, 0, 0, 0};
  for (int m = 0; m < 80; ++m) {
    const float w = ws[W1T + m * 256 + j];
#pragma unroll
    for (int q = 0; q < 8; ++q) {
      const int t = tg * 8 + q;
      const float x = (t > 0) ? din[((size_t)b * 80 + m) * 800 + (t - 1)] : 0.f;
      acc[q] = fmaf(x, w, acc[q]);
    }
  }
#pragma unroll
  for (int q = 0; q < 8; ++q) h1[q][j] = fmaxf(acc[q], 0.f);
  __syncthreads();
  float a2[8] = {0, 0, 0, 0, 0, 0, 0, 0};
  for (int k = 0; k < 256; ++k) {
    const float w = ws[W2T + k * 256 + j];
#pragma unroll
    for (int q = 0; q < 8; ++q) a2[q] = fmaf(h1[q][k], w, a2[q]);
  }
#pragma unroll
  for (int q = 0; q < 8; ++q) {
    const int t = tg * 8 + q;
    ws[PREN_O + ((size_t)t * 32 + b) * 256 + j] = fmaxf(a2[q], 0.f);
  }
}

__global__ __launch_bounds__(256) void k_pmem(const float* __restrict__ mem,
                                              float* __restrict__ ws) {
  __shared__ float mt[16 * 516];
  const int b = blockIdx.x, tc = blockIdx.y, tid = threadIdx.x;
  const int ti0 = tc * 16;
  for (int i = tid; i < 16 * 128; i += 256) {
    const int r = i >> 7, c = i & 127;
    *(float4*)(mt + r * 516 + c * 4) =
        *(const float4*)(mem + ((size_t)b * 512 + ti0 + r) * 512 + c * 4);
  }
  __syncthreads();
  const int a = tid & 127, th = tid >> 7;
  float acc[8] = {0, 0, 0, 0, 0, 0, 0, 0};
  for (int e = 0; e < 512; ++e) {
    const float w = ws[MEMWT + (size_t)e * 128 + a];
#pragma unroll
    for (int q = 0; q < 8; ++q) acc[q] = fmaf(w, mt[(th * 8 + q) * 516 + e], acc[q]);
  }
#pragma unroll
  for (int q = 0; q < 8; ++q)
    ws[PMEMT + ((size_t)b * 128 + a) * 512 + ti0 + th * 8 + q] = acc[q];
}

// ---------------- main persistent kernel ----------------
struct TP {
  const float *mem, *abih, *abhh, *lconv, *llw, *vw, *dbih, *dbhh, *projb, *gateb;
  const int* lens;
  float* ws;
  float* out;
};

__global__ __launch_bounds__(256) void taco_main(TP p) {
  __shared__ float smem[8320];
  float* const ws = p.ws;
  const int bid = blockIdx.x, tid = threadIdx.x;

#pragma unroll 1
  for (int t = 0; t <= 800; ++t) {
    const int par = t & 1;
    // ---- S1: att-GEMM(t) [192 blocks] ; dec-actx-GEMM(t-1) [64 blocks]
    if (bid < 192) {
      if (t < 800) {
        const int ks = bid >> 6, gb = bid & 63;
        const int klo = ks * 600, khi = (ks == 2) ? 1792 : klo + 600;
        gemm_partial(ws + XATT + (size_t)par * 57344, 1792, ws + WT_ATT, klo, khi,
                     ws + ZATT_O + (size_t)ks * 131072, gb, tid, smem);
      }
    } else if (t > 0) {
      gemm_partial(ws + XDEC, 2560, ws + WT_DEC, 2048, 2560,
                   ws + ZDEC_O + 3ull * 131072, bid - 192, tid, smem);
    }
    gsync();

    // ---- S2: att-cell(t) [128 blocks] ; dec-cell(t-1) [128 blocks]
    if (bid < 128) {
      if (t < 800) {
        const int idx = bid * 256 + tid, b = idx >> 10, j = idx & 1023;
        const float* zp = ws + ZATT_O + (size_t)b * 4096;
        float zi = zp[j] + zp[131072 + j] + zp[262144 + j] + p.abih[j] + p.abhh[j];
        float zf = zp[1024 + j] + zp[131072 + 1024 + j] + zp[262144 + 1024 + j] +
                   p.abih[1024 + j] + p.abhh[1024 + j];
        float zg = zp[2048 + j] + zp[131072 + 2048 + j] + zp[262144 + 2048 + j] +
                   p.abih[2048 + j] + p.abhh[2048 + j];
        float zo = zp[3072 + j] + zp[131072 + 3072 + j] + zp[262144 + 3072 + j] +
                   p.abih[3072 + j] + p.abhh[3072 + j];
        const float cp = ws[AC_O + (size_t)b * 1024 + j];
        const float ct = sigf(zf) * cp + sigf(zi) * tanh_f(zg);
        const float h = sigf(zo) * tanh_f(ct);
        ws[AC_O + (size_t)b * 1024 + j] = ct;
        ws[AH_O + (size_t)b * 1024 + j] = h;
        ws[XATT + (size_t)((t + 1) & 1) * 57344 + (size_t)b * 1792 + 768 + j] = h;
        ws[XDEC + (size_t)b * 2560 + j] = h;
      }
    } else if (t > 0) {
      const int idx = (bid - 128) * 256 + tid, b = idx >> 10, j = idx & 1023;
      const float* zp = ws + ZDEC_O + (size_t)b * 4096;
      float zi = zp[j] + zp[131072 + j] + zp[262144 + j] + zp[393216 + j] +
                 p.dbih[j] + p.dbhh[j];
      float zf = zp[1024 + j] + zp[131072 + 1024 + j] + zp[262144 + 1024 + j] +
                 zp[393216 + 1024 + j] + p.dbih[1024 + j] + p.dbhh[1024 + j];
      float zg = zp[2048 + j] + zp[131072 + 2048 + j] + zp[262144 + 2048 + j] +
                 zp[393216 + 2048 + j] + p.dbih[2048 + j] + p.dbhh[2048 + j];
      float zo = zp[3072 + j] + zp[131072 + 3072 + j] + zp[262144 + 3072 + j] +
                 zp[393216 + 3072 + j] + p.dbih[3072 + j] + p.dbhh[3072 + j];
      const float cp = ws[DC_O + (size_t)b * 1024 + j];
      const float ct = sigf(zf) * cp + sigf(zi) * tanh_f(zg);
      const float h = sigf(zo) * tanh_f(ct);
      ws[DC_O + (size_t)b * 1024 + j] = ct;
      ws[DH_O + (size_t)b * 1024 + j] = h;
      ws[XDEC + (size_t)b * 2560 + 1024 + j] = h;
    }
    gsync();

    // ---- S3: dec-[ah|dh]-GEMM(t) [192] ; energies(t)+pq+proj(t-1) [64]
    if (bid < 192) {
      if (t < 800) {
        const int ks = bid >> 6, gb = bid & 63;
        const int klo = ks * 684, khi = (ks == 2) ? 2048 : klo + 684;
        gemm_partial(ws + XDEC, 2560, ws + WT_DEC, klo, khi,
                     ws + ZDEC_O + (size_t)ks * 131072, gb, tid, smem);
      }
    } else {
      const int e = bid - 192, b = e >> 1, half = e & 1;
      const int tbase = half * 256;
      float* sm_pqp = smem;        // 256
      float* sm_pq = smem + 256;   // 128
      float* sm_a0 = smem + 384;   // 288 (aw halo)
      float* sm_a1 = smem + 672;   // 288 (awc halo)
      if (t < 800) {
        {  // pq partials: pq[b][j] = sum_k ah[b][k]*qw[j][k]
          const int j = tid & 127, kh = tid >> 7;
          float acc = 0;
          const float* qcol = ws + QWT + j;
          const float* ahr = ws + AH_O + (size_t)b * 1024 + kh * 512;
          for (int k = 0; k < 512; ++k)
            acc = fmaf(qcol[(size_t)(kh * 512 + k) * 128], ahr[k], acc);
          sm_pqp[tid] = acc;
        }
        for (int i = tid; i < 286; i += 256) {
          const int ti = tbase - 15 + i;
          const bool ok = (unsigned)ti < 512u;
          sm_a0[i] = ok ? ws[AW_O + (size_t)b * 512 + ti] : 0.f;
          sm_a1[i] = ok ? ws[AWC_O + (size_t)b * 512 + ti] : 0.f;
        }
        __syncthreads();
        if (tid < 128) sm_pq[tid] = sm_pqp[tid] + sm_pqp[128 + tid];
        __syncthreads();
        // per-thread: one t_in position
        float wa[31], wcc[31];
#pragma unroll
        for (int k2 = 0; k2 < 31; ++k2) {
          wa[k2] = sm_a0[tid + k2];
          wcc[k2] = sm_a1[tid + k2];
        }
        float loc[32];
#pragma unroll 1
        for (int f = 0; f < 32; ++f) {
          const float* wf = p.lconv + f * 62;
          float acc = 0;
#pragma unroll
          for (int k2 = 0; k2 < 31; ++k2) acc = fmaf(wa[k2], wf[k2], acc);
#pragma unroll
          for (int k2 = 0; k2 < 31; ++k2) acc = fmaf(wcc[k2], wf[31 + k2], acc);
          loc[f] = acc;
        }
        const int ti = tbase + tid;
        const float* pmcol = ws + PMEMT + (size_t)b * 128 * 512 + ti;
        float acc_e = 0;
#pragma unroll 1
        for (int a = 0; a < 128; ++a) {
          float s = sm_pq[a] + pmcol[(size_t)a * 512];
          const float* la = p.llw + a * 32;
#pragma unroll
          for (int f = 0; f < 32; ++f) s = fmaf(loc[f], la[f], s);
          acc_e = fmaf(p.vw[a], tanh_f(s), acc_e);
        }
        ws[ENER_O + (size_t)b * 512 + ti] = (ti < p.lens[b]) ? acc_e : -1e9f;
      }
      if (t > 0) {  // proj(t-1): 81 outputs, K=1536 split into 6 segments
        __syncthreads();
        const int oi = tid / 6, ksg = tid - oi * 6;
        float part = 0.f;
        if (oi < 41) {
          const int o = half * 41 + oi;  // o==81 reads zero pad, discarded
          const int k0 = ksg * 256;
          const float* xh = ws + DH_O + (size_t)b * 1024;
          const float* xa = ws + ACTX_O + (size_t)((t - 1) & 1) * 16384 + (size_t)b * 512;
          const float* wcol = ws + PWT + o;
          for (int k = k0; k < k0 + 256; ++k) {
            const float x = (k < 1024) ? xh[k] : xa[k - 1024];
            part = fmaf(x, wcol[(size_t)k * 96], part);
          }
        }
        __syncthreads();
        smem[tid] = part;
        __syncthreads();
        const int cnt = half ? 40 : 41;
        if (tid < cnt) {
          const int o = half * 41 + tid;
          float ssum = 0;
#pragma unroll
          for (int q = 0; q < 6; ++q) ssum += smem[tid * 6 + q];
          ssum += (o < 80) ? p.projb[o] : p.gateb[0];
          if (o < 80) p.out[MEL_OUT + ((size_t)b * 80 + o) * 800 + (t - 1)] = ssum;
          else p.out[GATE_OUT + (size_t)b * 800 + (t - 1)] = ssum;
        }
      }
    }
    gsync();

    // ---- S4: softmax + context  [256 blocks: b = bid>>3, d-chunk = bid&7]
    if (t < 800) {
      const int b = bid >> 3, dc8 = bid & 7;
      float* sm_p = smem;        // 512
      float* sm_r = smem + 512;  // 256
      float* sm_c = smem + 768;  // 256
      const float e0 = ws[ENER_O + (size_t)b * 512 + tid];
      const float e1 = ws[ENER_O + (size_t)b * 512 + 256 + tid];
      sm_r[tid] = fmaxf(e0, e1);
      __syncthreads();
      for (int s = 128; s > 0; s >>= 1) {
        if (tid < s) sm_r[tid] = fmaxf(sm_r[tid], sm_r[tid + s]);
        __syncthreads();
      }
      const float mx = sm_r[0];
      __syncthreads();
      const float p0 = __expf(e0 - mx), p1 = __expf(e1 - mx);
      sm_p[tid] = p0;
      sm_p[256 + tid] = p1;
      sm_r[tid] = p0 + p1;
      __syncthreads();
      for (int s = 128; s > 0; s >>= 1) {
        if (tid < s) sm_r[tid] += sm_r[tid + s];
        __syncthreads();
      }
      const float inv = 1.f / sm_r[0];
      const int tseg = tid >> 6, dl = tid & 63;
      const int d = dc8 * 64 + dl;
      const float* mrow = p.mem + ((size_t)b * 512 + tseg * 128) * 512 + d;
      float acc = 0;
      for (int i = 0; i < 128; ++i) acc = fmaf(sm_p[tseg * 128 + i], mrow[(size_t)i * 512], acc);
      sm_c[tid] = acc;
      __syncthreads();
      if (tid < 64) {
        const float v =
            (sm_c[tid] + sm_c[64 + tid] + sm_c[128 + tid] + sm_c[192 + tid]) * inv;
        const int dd = dc8 * 64 + tid;
        ws[ACTX_O + (size_t)(t & 1) * 16384 + (size_t)b * 512 + dd] = v;
        ws[XATT + (size_t)((t + 1) & 1) * 57344 + (size_t)b * 1792 + 256 + dd] = v;
        ws[XDEC + (size_t)b * 2560 + 2048 + dd] = v;
      }
      if (dc8 == 0) {
        const float a0 = p0 * inv, a1 = p1 * inv;
        ws[AW_O + (size_t)b * 512 + tid] = a0;
        ws[AW_O + (size_t)b * 512 + 256 + tid] = a1;
        ws[AWC_O + (size_t)b * 512 + tid] += a0;
        ws[AWC_O + (size_t)b * 512 + 256 + tid] += a1;
        p.out[ALIGN_OUT + ((size_t)b * 800 + t) * 512 + tid] = a0;
        p.out[ALIGN_OUT + ((size_t)b * 800 + t) * 512 + 256 + tid] = a1;
      }
      if (dc8 == 1 && t + 1 < 800) {
        ws[XATT + (size_t)((t + 1) & 1) * 57344 + (size_t)b * 1792 + tid] =
            ws[PREN_O + ((size_t)(t + 1) * 32 + b) * 256 + tid];
      }
    }
    gsync();
  }
}

// ---------------- launch ----------------
extern "C" void kernel_launch(void* const* d_in, const int* in_sizes, int n_in,
                              void* d_out, int out_size, void* d_ws, size_t ws_size,
                              hipStream_t stream) {
  (void)in_sizes; (void)n_in; (void)out_size; (void)ws_size;
  const float* mem = (const float*)d_in[0];
  const float* decin = (const float*)d_in[1];
  const float* w1 = (const float*)d_in[2];
  const float* w2 = (const float*)d_in[3];
  const float* awih = (const float*)d_in[4];
  const float* awhh = (const float*)d_in[5];
  const float* abih = (const float*)d_in[6];
  const float* abhh = (const float*)d_in[7];
  const float* qw = (const float*)d_in[8];
  const float* memw = (const float*)d_in[9];
  const float* vw = (const float*)d_in[10];
  const float* lconv = (const float*)d_in[11];
  const float* llw = (const float*)d_in[12];
  const float* dwih = (const float*)d_in[13];
  const float* dwhh = (const float*)d_in[14];
  const float* dbih = (const float*)d_in[15];
  const float* dbhh = (const float*)d_in[16];
  const float* projw = (const float*)d_in[17];
  const float* projb = (const float*)d_in[18];
  const float* gatew = (const float*)d_in[19];
  const float* gateb = (const float*)d_in[20];
  const int* lens = (const int*)d_in[21];
  float* ws = (float*)d_ws;
  float* out = (float*)d_out;

  // zero state (AH..ACTX contiguous = 196608 floats) and Xatt[0] (pren[0]==0)
  hipMemsetAsync(ws + AH_O, 0, 196608 * sizeof(float), stream);
  hipMemsetAsync(ws + XATT, 0, 57344 * sizeof(float), stream);

  k_small<<<1680, 256, 0, stream>>>(w1, w2, qw, memw, projw, gatew, ws);
  k_wt_att<<<28672, 256, 0, stream>>>(awih, awhh, ws);
  k_wt_dec<<<40960, 256, 0, stream>>>(dwih, dwhh, ws);
  k_prenet<<<dim3(100, 32), 256, 0, stream>>>(decin, ws);
  k_xdec0<<<128, 256, 0, stream>>>(ws);
  k_pmem<<<dim3(32, 32), 256, 0, stream>>>(mem, ws);

  TP tp{mem, abih, abhh, lconv, llw, vw, dbih, dbhh, projb, gateb, lens, ws, out};
  taco_main<<<256, 256, 0, stream>>>(tp);
}

// Round 3
// 291345.483 us; speedup vs baseline: 2.2156x; 2.2156x over previous
//
#include <hip/hip_runtime.h>
#include <cstddef>

// ---------------- problem constants ----------------
// B=32, T_IN=512, T_OUT=800, N_MEL=80, ENC=512, ARNN=DRNN=1024, PRE=256,
// ATT=128, LOCF=32, LOCK=31.  4*ARNN = 4096 gate rows.

// ---------------- workspace layout (float offsets) ----------------
constexpr size_t WT_ATT = 0;                            // [1792][4096]
constexpr size_t WT_DEC = WT_ATT + 1792ull * 4096;      // [2560][4096]
constexpr size_t PREN_O = WT_DEC + 2560ull * 4096;      // [800][32][256]
constexpr size_t PMEMT  = PREN_O + 800ull * 32 * 256;   // [32][128][512]
constexpr size_t W1T    = PMEMT + 32ull * 128 * 512;    // [80][256]
constexpr size_t W2T    = W1T + 80 * 256;               // [256][256]
constexpr size_t QWT    = W2T + 256 * 256;              // [1024][128]
constexpr size_t PWT    = QWT + 1024 * 128;             // [1536][96] (cols 0..79 mel, 80 gate)
constexpr size_t MEMWT  = PWT + 1536 * 96;              // [512][128]
constexpr size_t XATT   = MEMWT + 512 * 128;            // [2][32][1792]  (pren|actx|ah)
constexpr size_t XDEC   = XATT + 2ull * 32 * 1792;      // [32][2560]     (ah|dh|actx)
constexpr size_t AH_O   = XDEC + 32ull * 2560;          // [32][1024]
constexpr size_t AC_O   = AH_O + 32 * 1024;
constexpr size_t DH_O   = AC_O + 32 * 1024;
constexpr size_t DC_O   = DH_O + 32 * 1024;
constexpr size_t AW_O   = DC_O + 32 * 1024;             // [32][512]
constexpr size_t AWC_O  = AW_O + 32 * 512;              // [32][512]
constexpr size_t ACTX_O = AWC_O + 32 * 512;             // [2][32][512]
constexpr size_t ENER_O = ACTX_O + 2ull * 32 * 512;     // [32][512]
constexpr size_t ZATT_O = ENER_O + 32 * 512;            // [3][32][4096]
constexpr size_t ZDEC_O = ZATT_O + 3ull * 32 * 4096;    // [4][32][4096]
constexpr size_t BAR_O  = ZDEC_O + 4ull * 32 * 4096;    // barrier counter (1 u32, 64B pad)

constexpr size_t MEL_OUT = 0;                 // [32][80][800]
constexpr size_t GATE_OUT = 2048000;          // [32][800]
constexpr size_t ALIGN_OUT = 2073600;         // [32][800][512]

// ---------------- software grid barrier ----------------
// Monotonic (reset-free) barrier in d_ws; counter memset to 0 at launch.
// RELAXED spin (no per-poll cache maintenance!), one release fence on arrive
// and one acquire fence on exit per block. __syncthreads() before arrival
// drains all waves' vmcnt, so lane-0's release fence covers the whole block.
__device__ __forceinline__ void gsync(unsigned* __restrict__ bar, unsigned& epoch) {
  __syncthreads();
  if (threadIdx.x == 0) {
    __builtin_amdgcn_fence(__ATOMIC_RELEASE, "agent");   // wbl2: push my L2 to MALL
    __hip_atomic_fetch_add(bar, 1u, __ATOMIC_RELAXED, __HIP_MEMORY_SCOPE_AGENT);
    ++epoch;
    const unsigned target = epoch * 256u;
    while (__hip_atomic_load(bar, __ATOMIC_RELAXED, __HIP_MEMORY_SCOPE_AGENT) < target) {
      __builtin_amdgcn_s_sleep(8);                       // ~512 cy poll pacing
    }
    __builtin_amdgcn_fence(__ATOMIC_ACQUIRE, "agent");   // inv: see others' writes
  }
  __syncthreads();
}

// ---------------- helpers ----------------
__device__ __forceinline__ float sigf(float x) {
  float cx = fminf(fmaxf(x, -30.f), 30.f);
  return 1.f / (1.f + __expf(-cx));
}
__device__ __forceinline__ float tanh_f(float x) {
  float cx = fminf(fmaxf(x, -15.f), 15.f);
  float e = __expf(2.f * cx);
  return (e - 1.f) / (e + 1.f);
}

// Z_partial[b][4096] for rows gb*64..gb*64+63, K range [klo,khi).
// X: [32][xstride], WT: [K][4096] transposed weights.
__device__ __forceinline__ void gemm_partial(
    const float* __restrict__ X, int xstride, const float* __restrict__ WT,
    int klo, int khi, float* __restrict__ zp, int gb, int tid, float* xs) {
  const int b = tid & 31, gt = tid >> 5;
  const int g0 = gb * 64 + gt * 8;
  float acc0 = 0, acc1 = 0, acc2 = 0, acc3 = 0, acc4 = 0, acc5 = 0, acc6 = 0, acc7 = 0;
  for (int kc = klo; kc < khi; kc += 256) {
    const int cn = (khi - kc < 256) ? (khi - kc) : 256;
    const int cn4 = cn >> 2;
    __syncthreads();
    for (int i = tid; i < 32 * cn4; i += 256) {
      const int r = i / cn4, c = i - r * cn4;
      *(float4*)(xs + r * 260 + c * 4) =
          *(const float4*)(X + (size_t)r * xstride + kc + c * 4);
    }
    __syncthreads();
    const float* wb = WT + (size_t)kc * 4096 + g0;
    for (int kk = 0; kk < cn; kk += 4) {
      const float4 xv = *(const float4*)(xs + b * 260 + kk);
      const float* w0p = wb + (size_t)kk * 4096;
#define GSTEP(J, XJ)                                                     \
  {                                                                      \
    const float4 wA = *(const float4*)(w0p + (size_t)(J) * 4096);        \
    const float4 wB = *(const float4*)(w0p + (size_t)(J) * 4096 + 4);    \
    acc0 = fmaf(XJ, wA.x, acc0); acc1 = fmaf(XJ, wA.y, acc1);            \
    acc2 = fmaf(XJ, wA.z, acc2); acc3 = fmaf(XJ, wA.w, acc3);            \
    acc4 = fmaf(XJ, wB.x, acc4); acc5 = fmaf(XJ, wB.y, acc5);            \
    acc6 = fmaf(XJ, wB.z, acc6); acc7 = fmaf(XJ, wB.w, acc7);            \
  }
      GSTEP(0, xv.x) GSTEP(1, xv.y) GSTEP(2, xv.z) GSTEP(3, xv.w)
#undef GSTEP
    }
  }
  float* zr = zp + (size_t)b * 4096 + g0;
  *(float4*)zr = make_float4(acc0, acc1, acc2, acc3);
  *(float4*)(zr + 4) = make_float4(acc4, acc5, acc6, acc7);
}

// ---------------- setup kernels ----------------
__global__ __launch_bounds__(256) void k_small(
    const float* __restrict__ w1, const float* __restrict__ w2,
    const float* __restrict__ qw, const float* __restrict__ memw,
    const float* __restrict__ projw, const float* __restrict__ gatew,
    float* __restrict__ ws) {
  size_t i = (size_t)blockIdx.x * 256 + threadIdx.x;
  if (i < 20480) { size_t j = i & 255, m = i >> 8; ws[W1T + m * 256 + j] = w1[j * 80 + m]; return; }
  i -= 20480;
  if (i < 65536) { size_t j = i & 255, k = i >> 8; ws[W2T + k * 256 + j] = w2[j * 256 + k]; return; }
  i -= 65536;
  if (i < 131072) { size_t j = i & 127, k = i >> 7; ws[QWT + k * 128 + j] = qw[j * 1024 + k]; return; }
  i -= 131072;
  if (i < 65536) { size_t a = i & 127, e = i >> 7; ws[MEMWT + e * 128 + a] = memw[a * 512 + e]; return; }
  i -= 65536;
  if (i < 147456) {
    size_t o = i % 96, k = i / 96;
    float v = 0.f;
    if (o < 80) v = projw[o * 1536 + k];
    else if (o == 80) v = gatew[k];
    ws[PWT + k * 96 + o] = v;
  }
}

__global__ __launch_bounds__(256) void k_wt_att(const float* __restrict__ wih,
                                                const float* __restrict__ whh,
                                                float* __restrict__ ws) {
  const size_t i = (size_t)blockIdx.x * 256 + threadIdx.x;  // = k*4096 + g
  const size_t g = i & 4095, k = i >> 12;
  ws[WT_ATT + i] = (k < 768) ? wih[g * 768 + k] : whh[g * 1024 + (k - 768)];
}

__global__ __launch_bounds__(256) void k_wt_dec(const float* __restrict__ wih,
                                                const float* __restrict__ whh,
                                                float* __restrict__ ws) {
  const size_t i = (size_t)blockIdx.x * 256 + threadIdx.x;
  const size_t g = i & 4095, k = i >> 12;
  float v;
  if (k < 1024) v = wih[g * 1536 + k];                       // ah part of wih
  else if (k < 2048) v = whh[g * 1024 + (k - 1024)];         // dh (whh)
  else v = wih[g * 1536 + 1024 + (k - 2048)];                // actx part of wih
  ws[WT_DEC + i] = v;
}

__global__ __launch_bounds__(256) void k_xdec0(float* __restrict__ ws) {
  const int i = blockIdx.x * 256 + threadIdx.x;  // < 32768
  const int b = i >> 10, j = i & 1023;
  ws[XDEC + (size_t)b * 2560 + 1024 + j] = 0.f;
}

__global__ __launch_bounds__(256) void k_prenet(const float* __restrict__ din,
                                                float* __restrict__ ws) {
  __shared__ float h1[8][257];
  const int tg = blockIdx.x, b = blockIdx.y, j = threadIdx.x;
  float acc[8] = {0, 0, 0, 0, 0, 0, 0, 0};
  for (int m = 0; m < 80; ++m) {
    const float w = ws[W1T + m * 256 + j];
#pragma unroll
    for (int q = 0; q < 8; ++q) {
      const int t = tg * 8 + q;
      const float x = (t > 0) ? din[((size_t)b * 80 + m) * 800 + (t - 1)] : 0.f;
      acc[q] = fmaf(x, w, acc[q]);
    }
  }
#pragma unroll
  for (int q = 0; q < 8; ++q) h1[q][j] = fmaxf(acc[q], 0.f);
  __syncthreads();
  float a2[8] = {0, 0, 0, 0, 0, 0, 0, 0};
  for (int k = 0; k < 256; ++k) {
    const float w = ws[W2T + k * 256 + j];
#pragma unroll
    for (int q = 0; q < 8; ++q) a2[q] = fmaf(h1[q][k], w, a2[q]);
  }
#pragma unroll
  for (int q = 0; q < 8; ++q) {
    const int t = tg * 8 + q;
    ws[PREN_O + ((size_t)t * 32 + b) * 256 + j] = fmaxf(a2[q], 0.f);
  }
}

__global__ __launch_bounds__(256) void k_pmem(const float* __restrict__ mem,
                                              float* __restrict__ ws) {
  __shared__ float mt[16 * 516];
  const int b = blockIdx.x, tc = blockIdx.y, tid = threadIdx.x;
  const int ti0 = tc * 16;
  for (int i = tid; i < 16 * 128; i += 256) {
    const int r = i >> 7, c = i & 127;
    *(float4*)(mt + r * 516 + c * 4) =
        *(const float4*)(mem + ((size_t)b * 512 + ti0 + r) * 512 + c * 4);
  }
  __syncthreads();
  const int a = tid & 127, th = tid >> 7;
  float acc[8] = {0, 0, 0, 0, 0, 0, 0, 0};
  for (int e = 0; e < 512; ++e) {
    const float w = ws[MEMWT + (size_t)e * 128 + a];
#pragma unroll
    for (int q = 0; q < 8; ++q) acc[q] = fmaf(w, mt[(th * 8 + q) * 516 + e], acc[q]);
  }
#pragma unroll
  for (int q = 0; q < 8; ++q)
    ws[PMEMT + ((size_t)b * 128 + a) * 512 + ti0 + th * 8 + q] = acc[q];
}

// ---------------- main persistent kernel ----------------
struct TP {
  const float *mem, *abih, *abhh, *lconv, *llw, *vw, *dbih, *dbhh, *projb, *gateb;
  const int* lens;
  float* ws;
  float* out;
};

__global__ __launch_bounds__(256) void taco_main(TP p) {
  __shared__ float smem[8320];
  float* const ws = p.ws;
  unsigned* const bar = (unsigned*)(ws + BAR_O);
  unsigned epoch = 0;
  const int bid = blockIdx.x, tid = threadIdx.x;

#pragma unroll 1
  for (int t = 0; t <= 800; ++t) {
    const int par = t & 1;
    // ---- S1: att-GEMM(t) [192 blocks] ; dec-actx-GEMM(t-1) [64 blocks]
    if (bid < 192) {
      if (t < 800) {
        const int ks = bid >> 6, gb = bid & 63;
        const int klo = ks * 600, khi = (ks == 2) ? 1792 : klo + 600;
        gemm_partial(ws + XATT + (size_t)par * 57344, 1792, ws + WT_ATT, klo, khi,
                     ws + ZATT_O + (size_t)ks * 131072, gb, tid, smem);
      }
    } else if (t > 0) {
      gemm_partial(ws + XDEC, 2560, ws + WT_DEC, 2048, 2560,
                   ws + ZDEC_O + 3ull * 131072, bid - 192, tid, smem);
    }
    gsync(bar, epoch);

    // ---- S2: att-cell(t) [128 blocks] ; dec-cell(t-1) [128 blocks]
    if (bid < 128) {
      if (t < 800) {
        const int idx = bid * 256 + tid, b = idx >> 10, j = idx & 1023;
        const float* zp = ws + ZATT_O + (size_t)b * 4096;
        float zi = zp[j] + zp[131072 + j] + zp[262144 + j] + p.abih[j] + p.abhh[j];
        float zf = zp[1024 + j] + zp[131072 + 1024 + j] + zp[262144 + 1024 + j] +
                   p.abih[1024 + j] + p.abhh[1024 + j];
        float zg = zp[2048 + j] + zp[131072 + 2048 + j] + zp[262144 + 2048 + j] +
                   p.abih[2048 + j] + p.abhh[2048 + j];
        float zo = zp[3072 + j] + zp[131072 + 3072 + j] + zp[262144 + 3072 + j] +
                   p.abih[3072 + j] + p.abhh[3072 + j];
        const float cp = ws[AC_O + (size_t)b * 1024 + j];
        const float ct = sigf(zf) * cp + sigf(zi) * tanh_f(zg);
        const float h = sigf(zo) * tanh_f(ct);
        ws[AC_O + (size_t)b * 1024 + j] = ct;
        ws[AH_O + (size_t)b * 1024 + j] = h;
        ws[XATT + (size_t)((t + 1) & 1) * 57344 + (size_t)b * 1792 + 768 + j] = h;
        ws[XDEC + (size_t)b * 2560 + j] = h;
      }
    } else if (t > 0) {
      const int idx = (bid - 128) * 256 + tid, b = idx >> 10, j = idx & 1023;
      const float* zp = ws + ZDEC_O + (size_t)b * 4096;
      float zi = zp[j] + zp[131072 + j] + zp[262144 + j] + zp[393216 + j] +
                 p.dbih[j] + p.dbhh[j];
      float zf = zp[1024 + j] + zp[131072 + 1024 + j] + zp[262144 + 1024 + j] +
                 zp[393216 + 1024 + j] + p.dbih[1024 + j] + p.dbhh[1024 + j];
      float zg = zp[2048 + j] + zp[131072 + 2048 + j] + zp[262144 + 2048 + j] +
                 zp[393216 + 2048 + j] + p.dbih[2048 + j] + p.dbhh[2048 + j];
      float zo = zp[3072 + j] + zp[131072 + 3072 + j] + zp[262144 + 3072 + j] +
                 zp[393216 + 3072 + j] + p.dbih[3072 + j] + p.dbhh[3072 + j];
      const float cp = ws[DC_O + (size_t)b * 1024 + j];
      const float ct = sigf(zf) * cp + sigf(zi) * tanh_f(zg);
      const float h = sigf(zo) * tanh_f(ct);
      ws[DC_O + (size_t)b * 1024 + j] = ct;
      ws[DH_O + (size_t)b * 1024 + j] = h;
      ws[XDEC + (size_t)b * 2560 + 1024 + j] = h;
    }
    gsync(bar, epoch);

    // ---- S3: dec-[ah|dh]-GEMM(t) [192] ; energies(t)+pq+proj(t-1) [64]
    if (bid < 192) {
      if (t < 800) {
        const int ks = bid >> 6, gb = bid & 63;
        const int klo = ks * 684, khi = (ks == 2) ? 2048 : klo + 684;
        gemm_partial(ws + XDEC, 2560, ws + WT_DEC, klo, khi,
                     ws + ZDEC_O + (size_t)ks * 131072, gb, tid, smem);
      }
    } else {
      const int e = bid - 192, b = e >> 1, half = e & 1;
      const int tbase = half * 256;
      float* sm_pqp = smem;        // 256
      float* sm_pq = smem + 256;   // 128
      float* sm_a0 = smem + 384;   // 288 (aw halo)
      float* sm_a1 = smem + 672;   // 288 (awc halo)
      if (t < 800) {
        {  // pq partials: pq[b][j] = sum_k ah[b][k]*qw[j][k]
          const int j = tid & 127, kh = tid >> 7;
          float acc = 0;
          const float* qcol = ws + QWT + j;
          const float* ahr = ws + AH_O + (size_t)b * 1024 + kh * 512;
          for (int k = 0; k < 512; ++k)
            acc = fmaf(qcol[(size_t)(kh * 512 + k) * 128], ahr[k], acc);
          sm_pqp[tid] = acc;
        }
        for (int i = tid; i < 286; i += 256) {
          const int ti = tbase - 15 + i;
          const bool ok = (unsigned)ti < 512u;
          sm_a0[i] = ok ? ws[AW_O + (size_t)b * 512 + ti] : 0.f;
          sm_a1[i] = ok ? ws[AWC_O + (size_t)b * 512 + ti] : 0.f;
        }
        __syncthreads();
        if (tid < 128) sm_pq[tid] = sm_pqp[tid] + sm_pqp[128 + tid];
        __syncthreads();
        // per-thread: one t_in position
        float wa[31], wcc[31];
#pragma unroll
        for (int k2 = 0; k2 < 31; ++k2) {
          wa[k2] = sm_a0[tid + k2];
          wcc[k2] = sm_a1[tid + k2];
        }
        float loc[32];
#pragma unroll 1
        for (int f = 0; f < 32; ++f) {
          const float* wf = p.lconv + f * 62;
          float acc = 0;
#pragma unroll
          for (int k2 = 0; k2 < 31; ++k2) acc = fmaf(wa[k2], wf[k2], acc);
#pragma unroll
          for (int k2 = 0; k2 < 31; ++k2) acc = fmaf(wcc[k2], wf[31 + k2], acc);
          loc[f] = acc;
        }
        const int ti = tbase + tid;
        const float* pmcol = ws + PMEMT + (size_t)b * 128 * 512 + ti;
        float acc_e = 0;
#pragma unroll 1
        for (int a = 0; a < 128; ++a) {
          float s = sm_pq[a] + pmcol[(size_t)a * 512];
          const float* la = p.llw + a * 32;
#pragma unroll
          for (int f = 0; f < 32; ++f) s = fmaf(loc[f], la[f], s);
          acc_e = fmaf(p.vw[a], tanh_f(s), acc_e);
        }
        ws[ENER_O + (size_t)b * 512 + ti] = (ti < p.lens[b]) ? acc_e : -1e9f;
      }
      if (t > 0) {  // proj(t-1): 81 outputs, K=1536 split into 6 segments
        __syncthreads();
        const int oi = tid / 6, ksg = tid - oi * 6;
        float part = 0.f;
        if (oi < 41) {
          const int o = half * 41 + oi;  // o==81 reads zero pad, discarded
          const int k0 = ksg * 256;
          const float* xh = ws + DH_O + (size_t)b * 1024;
          const float* xa = ws + ACTX_O + (size_t)((t - 1) & 1) * 16384 + (size_t)b * 512;
          const float* wcol = ws + PWT + o;
          for (int k = k0; k < k0 + 256; ++k) {
            const float x = (k < 1024) ? xh[k] : xa[k - 1024];
            part = fmaf(x, wcol[(size_t)k * 96], part);
          }
        }
        __syncthreads();
        smem[tid] = part;
        __syncthreads();
        const int cnt = half ? 40 : 41;
        if (tid < cnt) {
          const int o = half * 41 + tid;
          float ssum = 0;
#pragma unroll
          for (int q = 0; q < 6; ++q) ssum += smem[tid * 6 + q];
          ssum += (o < 80) ? p.projb[o] : p.gateb[0];
          if (o < 80) p.out[MEL_OUT + ((size_t)b * 80 + o) * 800 + (t - 1)] = ssum;
          else p.out[GATE_OUT + (size_t)b * 800 + (t - 1)] = ssum;
        }
      }
    }
    gsync(bar, epoch);

    // ---- S4: softmax + context  [256 blocks: b = bid>>3, d-chunk = bid&7]
    if (t < 800) {
      const int b = bid >> 3, dc8 = bid & 7;
      float* sm_p = smem;        // 512
      float* sm_r = smem + 512;  // 256
      float* sm_c = smem + 768;  // 256
      const float e0 = ws[ENER_O + (size_t)b * 512 + tid];
      const float e1 = ws[ENER_O + (size_t)b * 512 + 256 + tid];
      sm_r[tid] = fmaxf(e0, e1);
      __syncthreads();
      for (int s = 128; s > 0; s >>= 1) {
        if (tid < s) sm_r[tid] = fmaxf(sm_r[tid], sm_r[tid + s]);
        __syncthreads();
      }
      const float mx = sm_r[0];
      __syncthreads();
      const float p0 = __expf(e0 - mx), p1 = __expf(e1 - mx);
      sm_p[tid] = p0;
      sm_p[256 + tid] = p1;
      sm_r[tid] = p0 + p1;
      __syncthreads();
      for (int s = 128; s > 0; s >>= 1) {
        if (tid < s) sm_r[tid] += sm_r[tid + s];
        __syncthreads();
      }
      const float inv = 1.f / sm_r[0];
      const int tseg = tid >> 6, dl = tid & 63;
      const int d = dc8 * 64 + dl;
      const float* mrow = p.mem + ((size_t)b * 512 + tseg * 128) * 512 + d;
      float acc = 0;
      for (int i = 0; i < 128; ++i) acc = fmaf(sm_p[tseg * 128 + i], mrow[(size_t)i * 512], acc);
      sm_c[tid] = acc;
      __syncthreads();
      if (tid < 64) {
        const float v =
            (sm_c[tid] + sm_c[64 + tid] + sm_c[128 + tid] + sm_c[192 + tid]) * inv;
        const int dd = dc8 * 64 + tid;
        ws[ACTX_O + (size_t)(t & 1) * 16384 + (size_t)b * 512 + dd] = v;
        ws[XATT + (size_t)((t + 1) & 1) * 57344 + (size_t)b * 1792 + 256 + dd] = v;
        ws[XDEC + (size_t)b * 2560 + 2048 + dd] = v;
      }
      if (dc8 == 0) {
        const float a0 = p0 * inv, a1 = p1 * inv;
        ws[AW_O + (size_t)b * 512 + tid] = a0;
        ws[AW_O + (size_t)b * 512 + 256 + tid] = a1;
        ws[AWC_O + (size_t)b * 512 + tid] += a0;
        ws[AWC_O + (size_t)b * 512 + 256 + tid] += a1;
        p.out[ALIGN_OUT + ((size_t)b * 800 + t) * 512 + tid] = a0;
        p.out[ALIGN_OUT + ((size_t)b * 800 + t) * 512 + 256 + tid] = a1;
      }
      if (dc8 == 1 && t + 1 < 800) {
        ws[XATT + (size_t)((t + 1) & 1) * 57344 + (size_t)b * 1792 + tid] =
            ws[PREN_O + ((size_t)(t + 1) * 32 + b) * 256 + tid];
      }
    }
    gsync(bar, epoch);
  }
}

// ---------------- launch ----------------
extern "C" void kernel_launch(void* const* d_in, const int* in_sizes, int n_in,
                              void* d_out, int out_size, void* d_ws, size_t ws_size,
                              hipStream_t stream) {
  (void)in_sizes; (void)n_in; (void)out_size; (void)ws_size;
  const float* mem = (const float*)d_in[0];
  const float* decin = (const float*)d_in[1];
  const float* w1 = (const float*)d_in[2];
  const float* w2 = (const float*)d_in[3];
  const float* awih = (const float*)d_in[4];
  const float* awhh = (const float*)d_in[5];
  const float* abih = (const float*)d_in[6];
  const float* abhh = (const float*)d_in[7];
  const float* qw = (const float*)d_in[8];
  const float* memw = (const float*)d_in[9];
  const float* vw = (const float*)d_in[10];
  const float* lconv = (const float*)d_in[11];
  const float* llw = (const float*)d_in[12];
  const float* dwih = (const float*)d_in[13];
  const float* dwhh = (const float*)d_in[14];
  const float* dbih = (const float*)d_in[15];
  const float* dbhh = (const float*)d_in[16];
  const float* projw = (const float*)d_in[17];
  const float* projb = (const float*)d_in[18];
  const float* gatew = (const float*)d_in[19];
  const float* gateb = (const float*)d_in[20];
  const int* lens = (const int*)d_in[21];
  float* ws = (float*)d_ws;
  float* out = (float*)d_out;

  // zero state (AH..ACTX contiguous = 196608 floats), Xatt[0] (pren[0]==0),
  // and the barrier counter (monotonic within one launch).
  hipMemsetAsync(ws + AH_O, 0, 196608 * sizeof(float), stream);
  hipMemsetAsync(ws + XATT, 0, 57344 * sizeof(float), stream);
  hipMemsetAsync(ws + BAR_O, 0, 256, stream);

  k_small<<<1680, 256, 0, stream>>>(w1, w2, qw, memw, projw, gatew, ws);
  k_wt_att<<<28672, 256, 0, stream>>>(awih, awhh, ws);
  k_wt_dec<<<40960, 256, 0, stream>>>(dwih, dwhh, ws);
  k_prenet<<<dim3(100, 32), 256, 0, stream>>>(decin, ws);
  k_xdec0<<<128, 256, 0, stream>>>(ws);
  k_pmem<<<dim3(32, 32), 256, 0, stream>>>(mem, ws);

  TP tp{mem, abih, abhh, lconv, llw, vw, dbih, dbhh, projb, gateb, lens, ws, out};
  taco_main<<<256, 256, 0, stream>>>(tp);
}